// Round 7
// baseline (90.600 us; speedup 1.0000x reference)
//
#include <hip/hip_runtime.h>

// QCNNHybridModel: fused conv2x2+sigmoid -> RBF(16) -> Linear(16,32)+tanh -> Linear(32,1)+sigmoid
// One thread per sample; block of 128 threads stages its 128 samples (41.5 KB)
// into LDS with coalesced float4 loads, then computes from LDS.

constexpr int NPIX    = 81;   // 9*9
constexpr int RBF_IN  = 64;   // 8*8 conv outputs
constexpr int RBF_OUT = 16;
constexpr int HID     = 32;
constexpr int SPB     = 128;  // samples per block == threads per block

__device__ __forceinline__ float sigmoid_f(float v) {
    return __builtin_amdgcn_rcpf(1.0f + __expf(-v));
}

__device__ __forceinline__ float tanh_f(float v) {
    float vc = fminf(fmaxf(v, -15.0f), 15.0f);   // avoid inf/inf
    float e  = __expf(2.0f * vc);
    return (e - 1.0f) * __builtin_amdgcn_rcpf(e + 1.0f);
}

__global__ __launch_bounds__(SPB, 1) void qcnn_fused(
    const float* __restrict__ x,        // [B,1,9,9]
    const float* __restrict__ conv_w,   // [1,1,2,2]
    const float* __restrict__ conv_b,   // [1]
    const float* __restrict__ centers,  // [16,64]
    const float* __restrict__ w1,       // [16,32]
    const float* __restrict__ b1,       // [32]
    const float* __restrict__ w2,       // [32,1]
    const float* __restrict__ b2,       // [1]
    float* __restrict__ out,            // [B]
    int nB)
{
    __shared__ float s_x[SPB * NPIX];          // 41472 B, coalesced-staged input
    __shared__ float s_c2t[RBF_IN * RBF_OUT];  // [k][j] = -2*centers[j][k]
    __shared__ float s_cc[RBF_OUT];            // ||c_j||^2
    __shared__ float s_w1t[HID * RBF_OUT];     // [i][j] = w1[j][i]
    __shared__ float s_b1[HID];
    __shared__ float s_w2[HID];

    const int tid = threadIdx.x;

    // ---- coalesced stage of this block's 128 input rows ----
    {
        const size_t base  = (size_t)blockIdx.x * (SPB * NPIX);
        const size_t total = (size_t)nB * NPIX;
        if (base + (size_t)(SPB * NPIX) <= total) {
            // full tile: 10368 floats = 2592 float4 (block base is 16B-aligned:
            // SPB*NPIX*4 = 41472 bytes, 41472 % 16 == 0)
            const float4* __restrict__ xv = (const float4*)(x + base);
            float4* sv = (float4*)s_x;
            #pragma unroll
            for (int i = 0; i < (SPB * NPIX / 4) / SPB; ++i)       // 20 full rounds
                sv[i * SPB + tid] = xv[i * SPB + tid];
            {   // remainder round: 2592 - 20*128 = 32 vectors
                int i = 20 * SPB + tid;
                if (i < SPB * NPIX / 4) sv[i] = xv[i];
            }
        } else {
            // tail block: scalar guarded
            for (int i = tid; i < SPB * NPIX; i += SPB) {
                size_t g = base + i;
                s_x[i] = (g < total) ? x[g] : 0.0f;
            }
        }
    }

    // ---- weights: ||a-c||^2 = ||a||^2 + a.(-2c) + ||c||^2 ----
    for (int idx = tid; idx < RBF_IN * RBF_OUT; idx += SPB) {
        int k = idx >> 4, j = idx & 15;
        s_c2t[idx] = -2.0f * centers[j * RBF_IN + k];
    }
    for (int idx = tid; idx < HID * RBF_OUT; idx += SPB) {
        int i = idx >> 4, j = idx & 15;
        s_w1t[idx] = w1[j * HID + i];
    }
    if (tid < HID) { s_b1[tid] = b1[tid]; s_w2[tid] = w2[tid]; }
    if (tid < RBF_OUT) {
        float s = 0.0f;
        for (int k = 0; k < RBF_IN; ++k) {
            float c = centers[tid * RBF_IN + k];
            s = fmaf(c, c, s);
        }
        s_cc[tid] = s;
    }
    __syncthreads();

    const int b = blockIdx.x * SPB + tid;
    if (b >= nB) return;

    // uniform scalar loads (compiler scalarizes)
    const float w00 = conv_w[0], w01 = conv_w[1], w10 = conv_w[2], w11 = conv_w[3];
    const float cbias = conv_b[0];

    // row from LDS: stride 81 words -> lane*81 mod 32 hits each bank exactly
    // twice across 64 lanes (2-way aliasing = free, m136)
    const float* __restrict__ row = &s_x[tid * NPIX];
    float xr[NPIX];
    #pragma unroll
    for (int i = 0; i < NPIX; ++i) xr[i] = row[i];

    float dot[RBF_OUT];
    #pragma unroll
    for (int j = 0; j < RBF_OUT; ++j) dot[j] = 0.0f;
    float S2 = 0.0f;

    #pragma unroll
    for (int r = 0; r < 8; ++r) {
        #pragma unroll
        for (int c = 0; c < 8; ++c) {
            float v = cbias;
            v = fmaf(w00, xr[r*9 + c],      v);
            v = fmaf(w01, xr[r*9 + c + 1],  v);
            v = fmaf(w10, xr[r*9 + 9 + c],  v);
            v = fmaf(w11, xr[r*9 + 10 + c], v);
            float a = sigmoid_f(v);               // sigmoid(logits - 0)
            S2 = fmaf(a, a, S2);
            const int k = r*8 + c;
            #pragma unroll
            for (int j = 0; j < RBF_OUT; ++j)
                dot[j] = fmaf(a, s_c2t[k*RBF_OUT + j], dot[j]);  // uniform addr -> broadcast
        }
    }

    float rbf[RBF_OUT];
    #pragma unroll
    for (int j = 0; j < RBF_OUT; ++j)
        rbf[j] = __expf(-(S2 + dot[j] + s_cc[j]));   // gamma = 1

    float acc = b2[0];
    #pragma unroll
    for (int i = 0; i < HID; ++i) {
        float hv = s_b1[i];
        #pragma unroll
        for (int j = 0; j < RBF_OUT; ++j)
            hv = fmaf(rbf[j], s_w1t[i*RBF_OUT + j], hv);
        acc = fmaf(tanh_f(hv), s_w2[i], acc);
    }
    out[b] = sigmoid_f(acc);
}

extern "C" void kernel_launch(void* const* d_in, const int* in_sizes, int n_in,
                              void* d_out, int out_size, void* d_ws, size_t ws_size,
                              hipStream_t stream) {
    const float* x       = (const float*)d_in[0];
    const float* conv_w  = (const float*)d_in[1];
    const float* conv_b  = (const float*)d_in[2];
    const float* centers = (const float*)d_in[3];
    const float* w1      = (const float*)d_in[4];
    const float* b1      = (const float*)d_in[5];
    const float* w2      = (const float*)d_in[6];
    const float* b2      = (const float*)d_in[7];
    float* out = (float*)d_out;

    int nB = out_size;                 // 65536
    int grid = (nB + SPB - 1) / SPB;   // 512 blocks
    qcnn_fused<<<grid, SPB, 0, stream>>>(x, conv_w, conv_b, centers,
                                         w1, b1, w2, b2, out, nB);
}

// Round 8
// 85.744 us; speedup vs baseline: 1.0566x; 1.0566x over previous
//
#include <hip/hip_runtime.h>

// QCNNHybridModel fused kernel, 2 lanes per sample for 2x wave count.
// conv2x2+sigmoid -> RBF(16) -> Linear(16,32)+tanh -> Linear(32,1)+sigmoid
// Block: 256 threads = 128 samples. Lane parity p owns conv-output rows 4p..4p+3
// and hidden units i = 2m+p; halves combined via __shfl_xor(.,1).

constexpr int NPIX    = 81;   // 9*9
constexpr int RBF_IN  = 64;   // 8*8 conv outputs
constexpr int RBF_OUT = 16;
constexpr int HID     = 32;
constexpr int SPB     = 128;  // samples per block
constexpr int TPB     = 256;  // threads per block

__device__ __forceinline__ float sigmoid_f(float v) {
    return __builtin_amdgcn_rcpf(1.0f + __expf(-v));
}

__device__ __forceinline__ float tanh_f(float v) {
    float vc = fminf(fmaxf(v, -15.0f), 15.0f);
    float e  = __expf(2.0f * vc);
    return (e - 1.0f) * __builtin_amdgcn_rcpf(e + 1.0f);
}

__global__ __launch_bounds__(TPB, 1) void qcnn_fused(
    const float* __restrict__ x,        // [B,1,9,9]
    const float* __restrict__ conv_w,   // [1,1,2,2]
    const float* __restrict__ conv_b,   // [1]
    const float* __restrict__ centers,  // [16,64]
    const float* __restrict__ w1,       // [16,32]
    const float* __restrict__ b1,       // [32]
    const float* __restrict__ w2,       // [32,1]
    const float* __restrict__ b2,       // [1]
    float* __restrict__ out,            // [B]
    int nB)
{
    __shared__ float s_x[SPB * NPIX];          // 41472 B staged input
    __shared__ float s_c2t[RBF_IN * RBF_OUT];  // [k][j] = -2*centers[j][k]
    __shared__ float s_cc[RBF_OUT];            // ||c_j||^2
    __shared__ float s_w1t[HID * RBF_OUT];     // [i][j] = w1[j][i]
    __shared__ float s_b1[HID];
    __shared__ float s_w2[HID];

    const int tid = threadIdx.x;

    // ---- coalesced stage of this block's 128 input rows (10368 floats) ----
    {
        const size_t base  = (size_t)blockIdx.x * (SPB * NPIX);
        const size_t total = (size_t)nB * NPIX;
        if (base + (size_t)(SPB * NPIX) <= total) {
            const float4* __restrict__ xv = (const float4*)(x + base);  // 41472B-aligned tile
            float4* sv = (float4*)s_x;
            #pragma unroll
            for (int i = 0; i < (SPB * NPIX / 4) / TPB; ++i)   // 10 full rounds
                sv[i * TPB + tid] = xv[i * TPB + tid];
            {   // remainder: 2592 - 10*256 = 32 vectors
                int i = 10 * TPB + tid;
                if (i < SPB * NPIX / 4) sv[i] = xv[i];
            }
        } else {
            for (int i = tid; i < SPB * NPIX; i += TPB) {
                size_t g = base + i;
                s_x[i] = (g < total) ? x[g] : 0.0f;
            }
        }
    }

    // ---- weights: ||a-c||^2 = ||a||^2 + a.(-2c) + ||c||^2 ----
    for (int idx = tid; idx < RBF_IN * RBF_OUT; idx += TPB) {
        int k = idx >> 4, j = idx & 15;
        s_c2t[idx] = -2.0f * centers[j * RBF_IN + k];
    }
    for (int idx = tid; idx < HID * RBF_OUT; idx += TPB) {
        int i = idx >> 4, j = idx & 15;
        s_w1t[idx] = w1[j * HID + i];
    }
    if (tid < HID) { s_b1[tid] = b1[tid]; s_w2[tid] = w2[tid]; }
    if (tid < RBF_OUT) {
        float s = 0.0f;
        for (int k = 0; k < RBF_IN; ++k) {
            float c = centers[tid * RBF_IN + k];
            s = fmaf(c, c, s);
        }
        s_cc[tid] = s;
    }
    __syncthreads();

    const int pair = tid >> 1;       // sample slot within block
    const int p    = tid & 1;        // which half of the sample this lane owns
    const int b    = blockIdx.x * SPB + pair;
    if (b >= nB) return;

    const float w00 = conv_w[0], w01 = conv_w[1], w10 = conv_w[2], w11 = conv_w[3];
    const float cbias = conv_b[0];

    // lane needs input rows 4p..4p+4 (5 rows x 9 = 45 floats)
    const float* __restrict__ row = &s_x[pair * NPIX + p * 36];
    float xr[45];
    #pragma unroll
    for (int i = 0; i < 45; ++i) xr[i] = row[i];

    float dotH[RBF_OUT];
    #pragma unroll
    for (int j = 0; j < RBF_OUT; ++j) dotH[j] = 0.0f;
    float S2h = 0.0f;

    #pragma unroll
    for (int r = 0; r < 4; ++r) {            // conv-output rows 4p + r
        #pragma unroll
        for (int c = 0; c < 8; ++c) {
            float v = cbias;
            v = fmaf(w00, xr[r*9 + c],      v);
            v = fmaf(w01, xr[r*9 + c + 1],  v);
            v = fmaf(w10, xr[r*9 + 9 + c],  v);
            v = fmaf(w11, xr[r*9 + 10 + c], v);
            float a = sigmoid_f(v);
            S2h = fmaf(a, a, S2h);
            const int k = (4*p + r)*8 + c;   // global feature index
            #pragma unroll
            for (int j = 0; j < RBF_OUT; ++j)
                dotH[j] = fmaf(a, s_c2t[k*RBF_OUT + j], dotH[j]);
        }
    }

    // combine halves (partner lane = tid^1, same sample)
    float S2 = S2h + __shfl_xor(S2h, 1);
    float rbf[RBF_OUT];
    #pragma unroll
    for (int j = 0; j < RBF_OUT; ++j) {
        float d = dotH[j] + __shfl_xor(dotH[j], 1);
        rbf[j] = __expf(-(S2 + d + s_cc[j]));     // gamma = 1
    }

    // classifier: lane p owns hidden units i = 2m + p
    float accH = 0.0f;
    #pragma unroll
    for (int m = 0; m < HID/2; ++m) {
        const int i = 2*m + p;
        float hv = s_b1[i];
        #pragma unroll
        for (int j = 0; j < RBF_OUT; ++j)
            hv = fmaf(rbf[j], s_w1t[i*RBF_OUT + j], hv);
        accH = fmaf(tanh_f(hv), s_w2[i], accH);
    }
    float acc = accH + __shfl_xor(accH, 1) + b2[0];
    if (p == 0) out[b] = sigmoid_f(acc);
}

extern "C" void kernel_launch(void* const* d_in, const int* in_sizes, int n_in,
                              void* d_out, int out_size, void* d_ws, size_t ws_size,
                              hipStream_t stream) {
    const float* x       = (const float*)d_in[0];
    const float* conv_w  = (const float*)d_in[1];
    const float* conv_b  = (const float*)d_in[2];
    const float* centers = (const float*)d_in[3];
    const float* w1      = (const float*)d_in[4];
    const float* b1      = (const float*)d_in[5];
    const float* w2      = (const float*)d_in[6];
    const float* b2      = (const float*)d_in[7];
    float* out = (float*)d_out;

    int nB = out_size;                 // 65536
    int grid = (nB + SPB - 1) / SPB;   // 512 blocks x 256 threads = 2 lanes/sample
    qcnn_fused<<<grid, TPB, 0, stream>>>(x, conv_w, conv_b, centers,
                                         w1, b1, w2, b2, out, nB);
}